// Round 6
// baseline (411.335 us; speedup 1.0000x reference)
//
#include <hip/hip_runtime.h>

#define NDIM 8
#define P_PAIRS 28
#define HID 128
#define BATCH_N 65536
#define TILE_M 256
#define THREADS 512
#define TILES_PER_BLOCK 4

#define LOG2E 1.4426950408889634f
#define LN2   0.6931471805599453f

typedef __attribute__((ext_vector_type(8))) _Float16 f16x8;
typedef __attribute__((ext_vector_type(2))) _Float16 f16x2;
typedef __attribute__((ext_vector_type(2))) unsigned short u16x2;
typedef __attribute__((ext_vector_type(4))) float f32x4;

// compiler-only fence: forbids reordering LDS stores/loads across it (TBAA guard)
#define MEM_FENCE asm volatile("" ::: "memory")

#define H2C(c) ((f16x2){(_Float16)(c), (_Float16)(c)})

__device__ __forceinline__ unsigned short f32_to_f16bits(float f) {
  _Float16 h = (_Float16)f;
  return __builtin_bit_cast(unsigned short, h);
}

// Packed-f16 trans-free softplus2: s(t) = log2(1+2^t) elementwise on a pair.
// u = clamp(-|t|, -12, 0); magic-add RNE split u = fl + f, f in [-0.5,0.5];
// 2^fl from exponent bits; 2^f Taylor cubic; log2(1+e) via sqrt2-shifted ln
// series deg-6. Max abs err ~2.5e-3 (poly + f16 rounding).
__device__ __forceinline__ f16x2 softplus2_pk(float t0, float t1) {
  f16x2 t = __builtin_bit_cast(f16x2, __builtin_amdgcn_cvt_pkrtz(t0, t1));
  f16x2 a = __builtin_elementwise_max(t, H2C(0.0f));
  f16x2 u = __builtin_elementwise_min(t, -t);          // -|t|
  u = __builtin_elementwise_max(u, H2C(-12.0f));
  f16x2 magic = H2C(1536.0f);
  f16x2 v = u + magic;                                 // RNE to integer (ulp=1)
  asm("" : "+v"(v));                                   // keep the round-trip
  f16x2 fl = v - magic;                                // round(u)
  f16x2 f = u - fl;                                    // frac in [-0.5, 0.5]
  u16x2 vb = __builtin_bit_cast(u16x2, v);
  u16x2 eb = (u16x2)(((vb & (u16x2){0x3FF, 0x3FF}) - (u16x2){497, 497}) << (u16x2){10, 10});
  f16x2 e2i = __builtin_bit_cast(f16x2, eb);           // 2^fl, fl in [-12,0]
  // 2^f, f in [-0.5,0.5]: Taylor deg-3 (rel err <8e-4)
  f16x2 p = H2C(1.0f) + f * (H2C(0.6931472f) + f * (H2C(0.2402265f) + f * H2C(0.0555041f)));
  f16x2 e = e2i * p;                                   // 2^u in (0, 1]
  // log2(1+e): m = 1+e in (1,2]; w = m/sqrt2 - 1 in (-0.293, 0.415]
  // log2(m) = 0.5 + log2e*ln(1+w), ln series deg-6
  f16x2 w = e * H2C(0.70710678f) + H2C(-0.29289322f);
  f16x2 r = ((((((H2C(-0.24044917f)) * w + H2C(0.28853901f)) * w + H2C(-0.36067376f)) * w
             + H2C(0.48089835f)) * w + H2C(-0.72134752f)) * w + H2C(1.44269504f)) * w + H2C(0.5f);
  return a + r;
}

// XOR-swizzled row-major [r][128] f16; element group c8 = k>>3 (16B granules)
__device__ __forceinline__ int swz(int r, int c8) {
  return r * 128 + (((c8 ^ (r & 15)) & 15) << 3);
}

// Transpose+convert: Wh (2,28,128,128) f32 -> WT f16, WT[l][p][n][k] = Wh[l][p][k][n]
__global__ void prep_wt(const float* __restrict__ Wh, unsigned short* __restrict__ WT) {
  __shared__ float tile[32][33];
  int t = blockIdx.x;           // 56*16 blocks
  int lp = t >> 4;
  int sub = t & 15;
  int kt = (sub >> 2) * 32, nt = (sub & 3) * 32;
  const float* src = Wh + (size_t)lp * 16384;
  unsigned short* dst = WT + (size_t)lp * 16384;
  int tx = threadIdx.x & 31, ty = threadIdx.x >> 5;   // 32 x 8
#pragma unroll
  for (int r = 0; r < 32; r += 8)
    tile[r + ty][tx] = src[(kt + r + ty) * 128 + (nt + tx)];
  __syncthreads();
#pragma unroll
  for (int r = 0; r < 32; r += 8)
    dst[(nt + r + ty) * 128 + (kt + tx)] = f32_to_f16bits(tile[tx][r + ty]);
}

__launch_bounds__(THREADS, 2)
__global__ void mlp_pairs(const float* __restrict__ x,
                          const float* __restrict__ W1,
                          const float* __restrict__ b1,
                          const float* __restrict__ bh,
                          const float* __restrict__ Wout,
                          const float* __restrict__ bout,
                          const int* __restrict__ rel_idx,
                          const int* __restrict__ i_idx,
                          const int* __restrict__ j_idx,
                          const unsigned short* __restrict__ WT,
                          float* __restrict__ out) {
  const int p = blockIdx.y;
  const int bx = blockIdx.x;          // batch group: rows [bx*1024, bx*1024+1024)
  const int tid = (int)threadIdx.x;
  const int lane = tid & 63;
  const int wave = tid >> 6;          // 0..7, each wave owns 32 rows per tile
  const int qd = lane >> 4;
  const int ln = lane & 15;
  const int mrow = wave * 32;

  __shared__ __align__(16) unsigned short w0_lds[128 * 128];   // 32 KB, swizzled [n][k]
  __shared__ __align__(16) unsigned short w1_lds[128 * 128];   // 32 KB, swizzled [n][k]
  __shared__ __align__(16) unsigned short h_lds[TILE_M * 128]; // 64 KB, swizzled [m][k]
  __shared__ __align__(16) unsigned short xg_lds[TILE_M][8];   //  4 KB
  __shared__ __align__(16) unsigned short w1t_lds[128][8];     //  2 KB
  __shared__ __align__(16) float b1s[128];
  __shared__ __align__(16) float bh0s[128];
  __shared__ __align__(16) float bh1s[128];
  __shared__ __align__(16) float wouts[128];
  // total ~139.3 KB -> 1 block/CU

  // ---- stage both hidden-layer weight slabs, swizzled (ONCE per block) ----
  {
    const uint4* s0 = reinterpret_cast<const uint4*>(WT + (size_t)p * 16384);
    const uint4* s1 = reinterpret_cast<const uint4*>(WT + (size_t)(P_PAIRS + p) * 16384);
#pragma unroll
    for (int it = 0; it < 4; ++it) {
      int idx = it * THREADS + tid;    // 0..2047
      int r = idx >> 4, c = idx & 15;
      uint4 a = s0[idx];
      uint4 b = s1[idx];
      int off = swz(r, c);
      *reinterpret_cast<uint4*>(&w0_lds[off]) = a;
      *reinterpret_cast<uint4*>(&w1_lds[off]) = b;
    }
  }
  if (tid < 128) {                      // W1^T prescaled by log2e, K padded 6->8
    int n = tid;
    unsigned short u[8];
#pragma unroll
    for (int k = 0; k < 6; ++k)
      u[k] = f32_to_f16bits(W1[(p * 6 + k) * 128 + n] * LOG2E);
    u[6] = 0; u[7] = 0;
    uint4 pk;
    pk.x = (unsigned)u[0] | ((unsigned)u[1] << 16);
    pk.y = (unsigned)u[2] | ((unsigned)u[3] << 16);
    pk.z = (unsigned)u[4] | ((unsigned)u[5] << 16);
    pk.w = 0u;
    *reinterpret_cast<uint4*>(&w1t_lds[n][0]) = pk;
  } else if (tid < 256) {
    int n = tid - 128;
    b1s[n]  = b1[p * 128 + n] * LOG2E;
    bh0s[n] = bh[p * 128 + n] * LOG2E;
    bh1s[n] = bh[(P_PAIRS + p) * 128 + n] * LOG2E;
    wouts[n] = Wout[p * 128 + n] * LN2;
  }
  int rl[6];
#pragma unroll
  for (int d = 0; d < 6; ++d) rl[d] = rel_idx[p * 6 + d];
  const int ii = i_idx[p], jj = j_idx[p];
  const float bp = bout[p];
  __syncthreads();   // the ONLY barrier

  // ---- preload hidden-layer biases into registers (used as MFMA C operand) ----
  f32x4 bh0r[8], bh1r[8];
#pragma unroll
  for (int nt = 0; nt < 8; ++nt) {
    bh0r[nt] = *reinterpret_cast<const f32x4*>(&bh0s[nt * 16 + qd * 4]);
    bh1r[nt] = *reinterpret_cast<const f32x4*>(&bh1s[nt * 16 + qd * 4]);
  }

  // ---- tile order: phase-staggered so SIMD-partner waves overlap epilogue/K-loop ----
  const int phase = (((wave & 1) ^ ((wave >> 2) & 1)) != 0) ? 2 : 0;

  // ---- prefetch first tile's x (lane<32: 32B row) ----
  float4 xa = {0.f, 0.f, 0.f, 0.f}, xb = {0.f, 0.f, 0.f, 0.f};
  {
    int row = bx * (TILE_M * TILES_PER_BLOCK) + phase * TILE_M + mrow + (lane & 31);
    const float4* xr = reinterpret_cast<const float4*>(x + (size_t)row * 8);
    if (lane < 32) { xa = xr[0]; xb = xr[1]; }
  }

  for (int s = 0; s < TILES_PER_BLOCK; ++s) {
    const int itile = (s + phase) & 3;
    const int row0 = bx * (TILE_M * TILES_PER_BLOCK) + itile * TILE_M;

    // ---- write gathered x rows (wave-private; no barrier needed) ----
    if (lane < 32) {
      int r = mrow + lane;             // local row in tile
      float xv[8] = {xa.x, xa.y, xa.z, xa.w, xb.x, xb.y, xb.z, xb.w};
      unsigned short u[8];
#pragma unroll
      for (int d = 0; d < 6; ++d)
        u[d] = f32_to_f16bits(xv[rl[d]]);
      u[6] = 0; u[7] = 0;
      uint4 pk;
      pk.x = (unsigned)u[0] | ((unsigned)u[1] << 16);
      pk.y = (unsigned)u[2] | ((unsigned)u[3] << 16);
      pk.z = (unsigned)u[4] | ((unsigned)u[5] << 16);
      pk.w = 0u;
      *reinterpret_cast<uint4*>(&xg_lds[r][0]) = pk;
    }
    MEM_FENCE;   // xg write -> layer-1 fragment read ordering
    // ---- prefetch next tile's x (overlaps this tile's compute) ----
    if (s + 1 < TILES_PER_BLOCK && lane < 32) {
      int nrow0 = bx * (TILE_M * TILES_PER_BLOCK) + (((s + 1 + phase) & 3)) * TILE_M;
      const float4* xr = reinterpret_cast<const float4*>(x + (size_t)(nrow0 + mrow + (lane & 31)) * 8);
      xa = xr[0]; xb = xr[1];
    }

    f32x4 acc[2][8];

    // ===== Layer 1: single K-step, bias as C operand =====
    {
      f16x8 zero8 = {};
      f16x8 bfr[2];
#pragma unroll
      for (int mt = 0; mt < 2; ++mt) {
        bfr[mt] = zero8;
        if (qd == 0)
          bfr[mt] = *reinterpret_cast<const f16x8*>(&xg_lds[mrow + mt * 16 + ln][0]);
      }
#pragma unroll
      for (int nt = 0; nt < 8; ++nt) {
        f16x8 afr = zero8;
        if (qd == 0)
          afr = *reinterpret_cast<const f16x8*>(&w1t_lds[nt * 16 + ln][0]);
        f32x4 b4 = *reinterpret_cast<const f32x4*>(&b1s[nt * 16 + qd * 4]);
#pragma unroll
        for (int mt = 0; mt < 2; ++mt)
          acc[mt][nt] = __builtin_amdgcn_mfma_f32_16x16x32_f16(afr, bfr[mt], b4, 0, 0, 0);
      }
    }
#pragma unroll
    for (int mt = 0; mt < 2; ++mt) {
      int m = mrow + mt * 16 + ln;
#pragma unroll
      for (int nt = 0; nt < 8; ++nt) {
        f16x2 s01 = softplus2_pk(acc[mt][nt][0], acc[mt][nt][1]);
        f16x2 s23 = softplus2_pk(acc[mt][nt][2], acc[mt][nt][3]);
        uint2 pk;
        pk.x = __builtin_bit_cast(unsigned, s01);
        pk.y = __builtin_bit_cast(unsigned, s23);
        int off = swz(m, nt * 2 + (qd >> 1)) + (qd & 1) * 4;
        *reinterpret_cast<uint2*>(&h_lds[off]) = pk;
      }
    }
    MEM_FENCE;   // layer-1 h write -> layer-2 fragment read ordering

    // ===== Layer 2: ks=0 peeled (bias as C), ks=1..3 accumulate =====
    {
      f16x8 bfr[2], afr[8];
#pragma unroll
      for (int mt = 0; mt < 2; ++mt)
        bfr[mt] = *reinterpret_cast<const f16x8*>(&h_lds[swz(mrow + mt * 16 + ln, qd)]);
#pragma unroll
      for (int nt = 0; nt < 8; ++nt)
        afr[nt] = *reinterpret_cast<const f16x8*>(&w0_lds[swz(nt * 16 + ln, qd)]);
#pragma unroll
      for (int nt = 0; nt < 8; ++nt)
#pragma unroll
        for (int mt = 0; mt < 2; ++mt)
          acc[mt][nt] = __builtin_amdgcn_mfma_f32_16x16x32_f16(afr[nt], bfr[mt], bh0r[nt], 0, 0, 0);
    }
#pragma unroll
    for (int ks = 1; ks < 4; ++ks) {
      f16x8 bfr[2], afr[8];
#pragma unroll
      for (int mt = 0; mt < 2; ++mt)
        bfr[mt] = *reinterpret_cast<const f16x8*>(&h_lds[swz(mrow + mt * 16 + ln, ks * 4 + qd)]);
#pragma unroll
      for (int nt = 0; nt < 8; ++nt)
        afr[nt] = *reinterpret_cast<const f16x8*>(&w0_lds[swz(nt * 16 + ln, ks * 4 + qd)]);
#pragma unroll
      for (int nt = 0; nt < 8; ++nt)
#pragma unroll
        for (int mt = 0; mt < 2; ++mt)
          acc[mt][nt] = __builtin_amdgcn_mfma_f32_16x16x32_f16(afr[nt], bfr[mt], acc[mt][nt], 0, 0, 0);
    }
#pragma unroll
    for (int mt = 0; mt < 2; ++mt) {
      int m = mrow + mt * 16 + ln;
#pragma unroll
      for (int nt = 0; nt < 8; ++nt) {
        f16x2 s01 = softplus2_pk(acc[mt][nt][0], acc[mt][nt][1]);
        f16x2 s23 = softplus2_pk(acc[mt][nt][2], acc[mt][nt][3]);
        uint2 pk;
        pk.x = __builtin_bit_cast(unsigned, s01);
        pk.y = __builtin_bit_cast(unsigned, s23);
        int off = swz(m, nt * 2 + (qd >> 1)) + (qd & 1) * 4;
        *reinterpret_cast<uint2*>(&h_lds[off]) = pk;
      }
    }
    MEM_FENCE;   // layer-2 h write -> layer-3 fragment read ordering

    // ===== Layer 3: ks=0 peeled (bias as C), then output dot =====
    {
      f16x8 bfr[2], afr[8];
#pragma unroll
      for (int mt = 0; mt < 2; ++mt)
        bfr[mt] = *reinterpret_cast<const f16x8*>(&h_lds[swz(mrow + mt * 16 + ln, qd)]);
#pragma unroll
      for (int nt = 0; nt < 8; ++nt)
        afr[nt] = *reinterpret_cast<const f16x8*>(&w1_lds[swz(nt * 16 + ln, qd)]);
#pragma unroll
      for (int nt = 0; nt < 8; ++nt)
#pragma unroll
        for (int mt = 0; mt < 2; ++mt)
          acc[mt][nt] = __builtin_amdgcn_mfma_f32_16x16x32_f16(afr[nt], bfr[mt], bh1r[nt], 0, 0, 0);
    }
#pragma unroll
    for (int ks = 1; ks < 4; ++ks) {
      f16x8 bfr[2], afr[8];
#pragma unroll
      for (int mt = 0; mt < 2; ++mt)
        bfr[mt] = *reinterpret_cast<const f16x8*>(&h_lds[swz(mrow + mt * 16 + ln, ks * 4 + qd)]);
#pragma unroll
      for (int nt = 0; nt < 8; ++nt)
        afr[nt] = *reinterpret_cast<const f16x8*>(&w1_lds[swz(nt * 16 + ln, ks * 4 + qd)]);
#pragma unroll
      for (int nt = 0; nt < 8; ++nt)
#pragma unroll
        for (int mt = 0; mt < 2; ++mt)
          acc[mt][nt] = __builtin_amdgcn_mfma_f32_16x16x32_f16(afr[nt], bfr[mt], acc[mt][nt], 0, 0, 0);
    }
    float pv[2] = {0.f, 0.f};
#pragma unroll
    for (int mt = 0; mt < 2; ++mt) {
#pragma unroll
      for (int nt = 0; nt < 8; ++nt) {
        f32x4 wo4 = *reinterpret_cast<const f32x4*>(&wouts[nt * 16 + qd * 4]);
        f16x2 s01 = softplus2_pk(acc[mt][nt][0], acc[mt][nt][1]);
        f16x2 s23 = softplus2_pk(acc[mt][nt][2], acc[mt][nt][3]);
        pv[mt] += (float)s01[0] * wo4[0] + (float)s01[1] * wo4[1]
                + (float)s23[0] * wo4[2] + (float)s23[1] * wo4[3];
      }
    }

#pragma unroll
    for (int mt = 0; mt < 2; ++mt) {
      float v = pv[mt];
      v += __shfl_xor(v, 16, 64);
      v += __shfl_xor(v, 32, 64);
      if (lane < 16) {
        int mg = row0 + mrow + mt * 16 + lane;
        float val = v + bp;
        out[mg * 64 + ii * 8 + jj] = val;
        out[mg * 64 + jj * 8 + ii] = -val;
        if (p == 0) {
#pragma unroll
          for (int d = 0; d < 8; ++d)
            out[mg * 64 + d * 9] = 0.f;
        }
      }
    }
    MEM_FENCE;   // tile s reads done before tile s+1 xg overwrite
  }
}

extern "C" void kernel_launch(void* const* d_in, const int* in_sizes, int n_in,
                              void* d_out, int out_size, void* d_ws, size_t ws_size,
                              hipStream_t stream) {
  const float* x    = (const float*)d_in[0];
  const float* W1   = (const float*)d_in[1];
  const float* b1   = (const float*)d_in[2];
  const float* Wh   = (const float*)d_in[3];
  const float* bh   = (const float*)d_in[4];
  const float* Wout = (const float*)d_in[5];
  const float* bout = (const float*)d_in[6];
  const int* rel    = (const int*)d_in[7];
  const int* iidx   = (const int*)d_in[8];
  const int* jidx   = (const int*)d_in[9];
  float* out = (float*)d_out;
  unsigned short* WT = (unsigned short*)d_ws;  // 2*28*128*128 f16 = 1.84 MB

  prep_wt<<<dim3(56 * 16), 256, 0, stream>>>(Wh, WT);
  dim3 grid(BATCH_N / (TILE_M * TILES_PER_BLOCK), P_PAIRS);   // (64, 28)
  mlp_pairs<<<grid, THREADS, 0, stream>>>(x, W1, b1, bh, Wout, bout, rel, iidx, jidx, WT, out);
}

// Round 7
// 314.553 us; speedup vs baseline: 1.3077x; 1.3077x over previous
//
#include <hip/hip_runtime.h>

#define NDIM 8
#define P_PAIRS 28
#define HID 128
#define BATCH_N 65536
#define TILE_M 256
#define THREADS 1024
#define TILES_PER_BLOCK 4

#define LOG2E 1.4426950408889634f
#define LN2   0.6931471805599453f

typedef __attribute__((ext_vector_type(8))) short bf16x8;
typedef __attribute__((ext_vector_type(4))) float f32x4;

// compiler-only fence: forbids reordering LDS stores/loads across it (TBAA guard)
#define MEM_FENCE asm volatile("" ::: "memory")

__device__ __forceinline__ unsigned short f32_to_bf16(float f) {
  union { float f; unsigned u; } v; v.f = f;
  unsigned r = v.u + 0x7FFFu + ((v.u >> 16) & 1u);
  return (unsigned short)(r >> 16);
}

__device__ __forceinline__ unsigned cvt_pk_bf16(float a, float b) {
  unsigned r;
  asm("v_cvt_pk_bf16_f32 %0, %1, %2" : "=v"(r) : "v"(a), "v"(b));
  return r;
}

__device__ __forceinline__ float fast_exp2(float x) {
  float r; asm("v_exp_f32 %0, %1" : "=v"(r) : "v"(x)); return r;
}
__device__ __forceinline__ float fast_log2(float x) {
  float r; asm("v_log_f32 %0, %1" : "=v"(r) : "v"(x)); return r;
}

// h' = log2(1 + 2^t), t = z*log2e. Clamp at 30: exact (identity region within f32
// precision for t>25) and launders any NaN (fminf returns the non-NaN operand).
__device__ __forceinline__ float softplus2(float t) {
  t = fminf(t, 30.0f);
  return fast_log2(1.0f + fast_exp2(t));
}

// XOR-swizzled row-major [r][128] bf16; element group c8 = k>>3 (16B granules)
__device__ __forceinline__ int swz(int r, int c8) {
  return r * 128 + (((c8 ^ (r & 15)) & 15) << 3);
}

// Transpose+convert: Wh (2,28,128,128) f32 -> WT bf16, WT[l][p][n][k] = Wh[l][p][k][n]
__global__ void prep_wt(const float* __restrict__ Wh, unsigned short* __restrict__ WT) {
  __shared__ float tile[32][33];
  int t = blockIdx.x;           // 56*16 blocks
  int lp = t >> 4;
  int sub = t & 15;
  int kt = (sub >> 2) * 32, nt = (sub & 3) * 32;
  const float* src = Wh + (size_t)lp * 16384;
  unsigned short* dst = WT + (size_t)lp * 16384;
  int tx = threadIdx.x & 31, ty = threadIdx.x >> 5;   // 32 x 8
#pragma unroll
  for (int r = 0; r < 32; r += 8)
    tile[r + ty][tx] = src[(kt + r + ty) * 128 + (nt + tx)];
  __syncthreads();
#pragma unroll
  for (int r = 0; r < 32; r += 8)
    dst[(nt + r + ty) * 128 + (kt + tx)] = f32_to_bf16(tile[tx][r + ty]);
}

__launch_bounds__(THREADS, 4)
__global__ void mlp_pairs(const float* __restrict__ x,
                          const float* __restrict__ W1,
                          const float* __restrict__ b1,
                          const float* __restrict__ bh,
                          const float* __restrict__ Wout,
                          const float* __restrict__ bout,
                          const int* __restrict__ rel_idx,
                          const int* __restrict__ i_idx,
                          const int* __restrict__ j_idx,
                          const unsigned short* __restrict__ WT,
                          float* __restrict__ out) {
  const int p = blockIdx.y;
  const int bx = blockIdx.x;          // batch group: rows [bx*1024, bx*1024+1024)
  const int tid = (int)threadIdx.x;
  const int lane = tid & 63;
  const int wave = tid >> 6;          // 0..15, each wave owns 16 rows per tile
  const int qd = lane >> 4;
  const int ln = lane & 15;
  const int mrow = wave * 16;

  __shared__ __align__(16) unsigned short w0_lds[128 * 128];   // 32 KB, swizzled [n][k]
  __shared__ __align__(16) unsigned short w1_lds[128 * 128];   // 32 KB, swizzled [n][k]
  __shared__ __align__(16) unsigned short h_lds[TILE_M * 128]; // 64 KB, swizzled [m][k]
  __shared__ __align__(16) unsigned short xg_lds[TILE_M][8];   //  4 KB
  __shared__ __align__(16) unsigned short w1t_lds[128][8];     //  2 KB
  __shared__ __align__(16) float b1s[128];
  __shared__ __align__(16) float bh0s[128];
  __shared__ __align__(16) float bh1s[128];
  __shared__ __align__(16) float wouts[128];
  // total ~139.3 KB -> 1 block/CU, 16 waves = 4 waves/SIMD

  // ---- stage both hidden-layer weight slabs, swizzled (ONCE per block) ----
  {
    const uint4* s0 = reinterpret_cast<const uint4*>(WT + (size_t)p * 16384);
    const uint4* s1 = reinterpret_cast<const uint4*>(WT + (size_t)(P_PAIRS + p) * 16384);
#pragma unroll
    for (int it = 0; it < 2; ++it) {
      int idx = it * THREADS + tid;    // 0..2047
      int r = idx >> 4, c = idx & 15;
      uint4 a = s0[idx];
      uint4 b = s1[idx];
      int off = swz(r, c);
      *reinterpret_cast<uint4*>(&w0_lds[off]) = a;
      *reinterpret_cast<uint4*>(&w1_lds[off]) = b;
    }
  }
  if (tid < 128) {                      // W1^T prescaled by log2e, K padded 6->8
    int n = tid;
    unsigned short u[8];
#pragma unroll
    for (int k = 0; k < 6; ++k)
      u[k] = f32_to_bf16(W1[(p * 6 + k) * 128 + n] * LOG2E);
    u[6] = 0; u[7] = 0;
    uint4 pk;
    pk.x = (unsigned)u[0] | ((unsigned)u[1] << 16);
    pk.y = (unsigned)u[2] | ((unsigned)u[3] << 16);
    pk.z = (unsigned)u[4] | ((unsigned)u[5] << 16);
    pk.w = 0u;
    *reinterpret_cast<uint4*>(&w1t_lds[n][0]) = pk;
  } else if (tid < 256) {
    int n = tid - 128;
    b1s[n]  = b1[p * 128 + n] * LOG2E;
    bh0s[n] = bh[p * 128 + n] * LOG2E;
    bh1s[n] = bh[(P_PAIRS + p) * 128 + n] * LOG2E;
    wouts[n] = Wout[p * 128 + n] * LN2;
  }
  int rl[6];
#pragma unroll
  for (int d = 0; d < 6; ++d) rl[d] = rel_idx[p * 6 + d];
  const int ii = i_idx[p], jj = j_idx[p];
  const float bp = bout[p];
  __syncthreads();   // the ONLY barrier

  // ---- tile order: phase-staggered; SIMD partners are wave, wave+4, wave+8, wave+12 ----
  const int phase = ((wave >> 2) & 1) * 2;

  // ---- prefetch first tile's x (lane<16: one 32B row each) ----
  float4 xa = {0.f, 0.f, 0.f, 0.f}, xb = {0.f, 0.f, 0.f, 0.f};
  {
    int row = bx * (TILE_M * TILES_PER_BLOCK) + phase * TILE_M + mrow + ln;
    const float4* xr = reinterpret_cast<const float4*>(x + (size_t)row * 8);
    if (lane < 16) { xa = xr[0]; xb = xr[1]; }
  }

  for (int s = 0; s < TILES_PER_BLOCK; ++s) {
    const int itile = (s + phase) & 3;
    const int row0 = bx * (TILE_M * TILES_PER_BLOCK) + itile * TILE_M;

    // ---- write gathered x rows (wave-private; no barrier needed) ----
    if (lane < 16) {
      int r = mrow + lane;             // local row in tile
      float xv[8] = {xa.x, xa.y, xa.z, xa.w, xb.x, xb.y, xb.z, xb.w};
      unsigned short u[8];
#pragma unroll
      for (int d = 0; d < 6; ++d)
        u[d] = f32_to_bf16(xv[rl[d]]);
      u[6] = 0; u[7] = 0;
      uint4 pk;
      pk.x = (unsigned)u[0] | ((unsigned)u[1] << 16);
      pk.y = (unsigned)u[2] | ((unsigned)u[3] << 16);
      pk.z = (unsigned)u[4] | ((unsigned)u[5] << 16);
      pk.w = 0u;
      *reinterpret_cast<uint4*>(&xg_lds[r][0]) = pk;
    }
    MEM_FENCE;   // xg write -> layer-1 fragment read ordering
    // ---- prefetch next tile's x (overlaps this tile's compute) ----
    if (s + 1 < TILES_PER_BLOCK && lane < 16) {
      int nrow0 = bx * (TILE_M * TILES_PER_BLOCK) + (((s + 1 + phase) & 3)) * TILE_M;
      const float4* xr = reinterpret_cast<const float4*>(x + (size_t)(nrow0 + mrow + ln) * 8);
      xa = xr[0]; xb = xr[1];
    }

    f32x4 acc[8];

    // ===== Layer 1: single K-step, bias (from LDS) as C operand =====
    {
      bf16x8 zero8 = {};
      bf16x8 bfr = zero8;
      if (qd == 0)
        bfr = *reinterpret_cast<const bf16x8*>(&xg_lds[mrow + ln][0]);
#pragma unroll
      for (int nt = 0; nt < 8; ++nt) {
        bf16x8 afr = zero8;
        if (qd == 0)
          afr = *reinterpret_cast<const bf16x8*>(&w1t_lds[nt * 16 + ln][0]);
        f32x4 b4 = *reinterpret_cast<const f32x4*>(&b1s[nt * 16 + qd * 4]);
        acc[nt] = __builtin_amdgcn_mfma_f32_16x16x32_bf16(afr, bfr, b4, 0, 0, 0);
      }
    }
    {
      int m = mrow + ln;
#pragma unroll
      for (int nt = 0; nt < 8; ++nt) {
        uint2 pk;
        pk.x = cvt_pk_bf16(softplus2(acc[nt][0]), softplus2(acc[nt][1]));
        pk.y = cvt_pk_bf16(softplus2(acc[nt][2]), softplus2(acc[nt][3]));
        int off = swz(m, nt * 2 + (qd >> 1)) + (qd & 1) * 4;
        *reinterpret_cast<uint2*>(&h_lds[off]) = pk;
      }
    }
    MEM_FENCE;   // layer-1 h write -> layer-2 fragment read ordering

    // ===== Layer 2: ks=0 peeled (bias as C), ks=1..3 accumulate =====
    {
      bf16x8 bfr = *reinterpret_cast<const bf16x8*>(&h_lds[swz(mrow + ln, qd)]);
#pragma unroll
      for (int nt = 0; nt < 8; ++nt) {
        bf16x8 afr = *reinterpret_cast<const bf16x8*>(&w0_lds[swz(nt * 16 + ln, qd)]);
        f32x4 b4 = *reinterpret_cast<const f32x4*>(&bh0s[nt * 16 + qd * 4]);
        acc[nt] = __builtin_amdgcn_mfma_f32_16x16x32_bf16(afr, bfr, b4, 0, 0, 0);
      }
    }
#pragma unroll
    for (int ks = 1; ks < 4; ++ks) {
      bf16x8 bfr = *reinterpret_cast<const bf16x8*>(&h_lds[swz(mrow + ln, ks * 4 + qd)]);
      bf16x8 afr[8];
#pragma unroll
      for (int nt = 0; nt < 8; ++nt)
        afr[nt] = *reinterpret_cast<const bf16x8*>(&w0_lds[swz(nt * 16 + ln, ks * 4 + qd)]);
#pragma unroll
      for (int nt = 0; nt < 8; ++nt)
        acc[nt] = __builtin_amdgcn_mfma_f32_16x16x32_bf16(afr[nt], bfr, acc[nt], 0, 0, 0);
    }
    {
      int m = mrow + ln;
#pragma unroll
      for (int nt = 0; nt < 8; ++nt) {
        uint2 pk;
        pk.x = cvt_pk_bf16(softplus2(acc[nt][0]), softplus2(acc[nt][1]));
        pk.y = cvt_pk_bf16(softplus2(acc[nt][2]), softplus2(acc[nt][3]));
        int off = swz(m, nt * 2 + (qd >> 1)) + (qd & 1) * 4;
        *reinterpret_cast<uint2*>(&h_lds[off]) = pk;
      }
    }
    MEM_FENCE;   // layer-2 h write -> layer-3 fragment read ordering

    // ===== Layer 3: ks=0 peeled (bias as C), then output dot =====
    {
      bf16x8 bfr = *reinterpret_cast<const bf16x8*>(&h_lds[swz(mrow + ln, qd)]);
#pragma unroll
      for (int nt = 0; nt < 8; ++nt) {
        bf16x8 afr = *reinterpret_cast<const bf16x8*>(&w1_lds[swz(nt * 16 + ln, qd)]);
        f32x4 b4 = *reinterpret_cast<const f32x4*>(&bh1s[nt * 16 + qd * 4]);
        acc[nt] = __builtin_amdgcn_mfma_f32_16x16x32_bf16(afr, bfr, b4, 0, 0, 0);
      }
    }
#pragma unroll
    for (int ks = 1; ks < 4; ++ks) {
      bf16x8 bfr = *reinterpret_cast<const bf16x8*>(&h_lds[swz(mrow + ln, ks * 4 + qd)]);
      bf16x8 afr[8];
#pragma unroll
      for (int nt = 0; nt < 8; ++nt)
        afr[nt] = *reinterpret_cast<const bf16x8*>(&w1_lds[swz(nt * 16 + ln, ks * 4 + qd)]);
#pragma unroll
      for (int nt = 0; nt < 8; ++nt)
        acc[nt] = __builtin_amdgcn_mfma_f32_16x16x32_bf16(afr[nt], bfr, acc[nt], 0, 0, 0);
    }
    float pv = 0.f;
#pragma unroll
    for (int nt = 0; nt < 8; ++nt) {
      f32x4 wo4 = *reinterpret_cast<const f32x4*>(&wouts[nt * 16 + qd * 4]);
#pragma unroll
      for (int r = 0; r < 4; ++r)
        pv += wo4[r] * softplus2(acc[nt][r]);
    }

    {
      float v = pv;
      v += __shfl_xor(v, 16, 64);
      v += __shfl_xor(v, 32, 64);
      if (lane < 16) {
        int mg = row0 + mrow + lane;
        float val = v + bp;
        out[mg * 64 + ii * 8 + jj] = val;
        out[mg * 64 + jj * 8 + ii] = -val;
        if (p == 0) {
#pragma unroll
          for (int d = 0; d < 8; ++d)
            out[mg * 64 + d * 9] = 0.f;
        }
      }
    }
    MEM_FENCE;   // tile s reads done before tile s+1 xg overwrite
  }
}

extern "C" void kernel_launch(void* const* d_in, const int* in_sizes, int n_in,
                              void* d_out, int out_size, void* d_ws, size_t ws_size,
                              hipStream_t stream) {
  const float* x    = (const float*)d_in[0];
  const float* W1   = (const float*)d_in[1];
  const float* b1   = (const float*)d_in[2];
  const float* Wh   = (const float*)d_in[3];
  const float* bh   = (const float*)d_in[4];
  const float* Wout = (const float*)d_in[5];
  const float* bout = (const float*)d_in[6];
  const int* rel    = (const int*)d_in[7];
  const int* iidx   = (const int*)d_in[8];
  const int* jidx   = (const int*)d_in[9];
  float* out = (float*)d_out;
  unsigned short* WT = (unsigned short*)d_ws;  // 2*28*128*128 bf16 = 1.84 MB

  prep_wt<<<dim3(56 * 16), 256, 0, stream>>>(Wh, WT);
  dim3 grid(BATCH_N / (TILE_M * TILES_PER_BLOCK), P_PAIRS);   // (64, 28)
  mlp_pairs<<<grid, THREADS, 0, stream>>>(x, W1, b1, bh, Wout, bout, rel, iidx, jidx, WT, out);
}